// Round 1
// baseline (376.052 us; speedup 1.0000x reference)
//
#include <hip/hip_runtime.h>
#include <cmath>

#define LSEQ   1024
#define NPROJ  4620
#define DINNER 1536
#define NH     12
#define HDIM   128
#define OFF_Z  0
#define OFF_X  1536
#define OFF_B  3072
#define OFF_C  3840
#define OFF_DT 4608

// ---------------- generic f32 GEMM: C[M,N] = A[M,K] * W[N,K]^T ----------------
// BM=BN=64, BK=16, 256 threads, 4x4 micro-tile per thread. M,K multiples of 64/16.
__global__ __launch_bounds__(256) void gemm_abt(const float* __restrict__ A,
    const float* __restrict__ W, float* __restrict__ C, int M, int N, int K) {
  __shared__ float As[16][68];
  __shared__ float Ws[16][68];
  const int m0 = blockIdx.y * 64, n0 = blockIdx.x * 64;
  const int tid = threadIdx.x;
  const int ty = tid >> 4, tx = tid & 15;
  const int r = tid >> 2, q = (tid & 3) * 4;
  float acc[4][4] = {};
  for (int k0 = 0; k0 < K; k0 += 16) {
    float4 va = *(const float4*)(A + (size_t)(m0 + r) * K + k0 + q);
    float4 vw = make_float4(0.f, 0.f, 0.f, 0.f);
    if (n0 + r < N) vw = *(const float4*)(W + (size_t)(n0 + r) * K + k0 + q);
    As[q + 0][r] = va.x; As[q + 1][r] = va.y; As[q + 2][r] = va.z; As[q + 3][r] = va.w;
    Ws[q + 0][r] = vw.x; Ws[q + 1][r] = vw.y; Ws[q + 2][r] = vw.z; Ws[q + 3][r] = vw.w;
    __syncthreads();
#pragma unroll
    for (int k = 0; k < 16; ++k) {
      float4 av = *(const float4*)&As[k][ty * 4];
      float4 bv = *(const float4*)&Ws[k][tx * 4];
      float a[4] = {av.x, av.y, av.z, av.w};
      float b[4] = {bv.x, bv.y, bv.z, bv.w};
#pragma unroll
      for (int i = 0; i < 4; ++i)
#pragma unroll
        for (int j = 0; j < 4; ++j) acc[i][j] = fmaf(a[i], b[j], acc[i][j]);
    }
    __syncthreads();
  }
#pragma unroll
  for (int i = 0; i < 4; ++i) {
    int row = m0 + ty * 4 + i;
#pragma unroll
    for (int j = 0; j < 4; ++j) {
      int col = n0 + tx * 4 + j;
      if (col < N) C[(size_t)row * N + col] = acc[i][j];
    }
  }
}

// ---------------- conv1d (depthwise, kernel 4, causal) + SiLU ----------------
__global__ __launch_bounds__(256) void conv_silu(const float* __restrict__ proj,
    const float* __restrict__ cw, const float* __restrict__ cb, float* __restrict__ xact) {
  int idx = blockIdx.x * 256 + threadIdx.x;   // over 1024*1536
  int c = idx % DINNER, t = idx / DINNER;
  float a = cb[c];
#pragma unroll
  for (int i = 0; i < 4; ++i) {
    int tt = t + i - 3;
    if (tt >= 0) a = fmaf(proj[(size_t)tt * NPROJ + OFF_X + c], cw[c * 4 + i], a);
  }
  xact[idx] = a / (1.f + expf(-a));           // silu
}

// ---------------- dt = softplus(dt_r)+bias ; Phi = cumsum(A*dt) ----------------
// one block per head, 256 threads * 4 t each, block-wide inclusive scan
__global__ __launch_bounds__(256) void dtphi(const float* __restrict__ proj,
    const float* __restrict__ A_log, const float* __restrict__ dt_bias,
    float* __restrict__ Phi, float* __restrict__ dts) {
  int h = blockIdx.x, tid = threadIdx.x;
  float Ac = -expf(A_log[h]);
  float bb = dt_bias[h];
  float v[4], s = 0.f;
#pragma unroll
  for (int u = 0; u < 4; ++u) {
    int t = tid * 4 + u;
    float xr = proj[(size_t)t * NPROJ + OFF_DT + h];
    float sp = (xr > 20.f) ? xr : log1pf(expf(xr));
    v[u] = sp + bb;
    s += v[u];
  }
  int lane = tid & 63, wv = tid >> 6;
  float ps = s;
#pragma unroll
  for (int d = 1; d < 64; d <<= 1) {
    float o = __shfl_up(ps, d);
    if (lane >= d) ps += o;
  }
  __shared__ float wsum[4];
  if (lane == 63) wsum[wv] = ps;
  __syncthreads();
  float off = 0.f;
  for (int w = 0; w < wv; ++w) off += wsum[w];
  float run = off + ps - s;  // exclusive prefix of this thread's 4 values
#pragma unroll
  for (int u = 0; u < 4; ++u) {
    int t = tid * 4 + u;
    run += v[u];
    Phi[t * NH + h] = Ac * run;   // cumsum(A*dt) = A * cumsum(dt), A const per head
    dts[t * NH + h] = v[u];
  }
}

// ---------------- fused SSM quadratic form (flash-style, lower-triangular) ----
// y[t,hd] = sum_{s<=t} exp(Phi_t + min(-Phi_s,80)) * dt_s * (C_t . B_s) * x[s,hd] + Dp*x[t,hd]
// block = (t-block 64, head, hd-half 64). S computed in regs, masked, staged via LDS.
__global__ __launch_bounds__(256) void ssm_quad(const float* __restrict__ proj,
    const float* __restrict__ xact, const float* __restrict__ Phi,
    const float* __restrict__ dts, const float* __restrict__ Dp, float* __restrict__ y) {
  const int tb = blockIdx.x, h = blockIdx.y, zh = blockIdx.z;
  const int tid = threadIdx.x;
  __shared__ float Cst[64][68];   // transposed: [d][i]
  __shared__ float Bst[64][68];   // transposed: [d][j]; reused as masked S[i][j]
  __shared__ float Xs[64][68];    // [j][c]
  __shared__ float phiT[64], eS[64], dS[64];
  const int t0 = tb * 64;
  const int ty = tid >> 4, tx = tid & 15;
  const int ri = ty * 4, cj = tx * 4;

  // stage C tile (transposed) + Phi rows, once
#pragma unroll
  for (int u = 0; u < 4; ++u) {
    int idx = tid + u * 256, i = idx >> 4, fq = (idx & 15) * 4;
    float4 v = *(const float4*)(proj + (size_t)(t0 + i) * NPROJ + OFF_C + h * 64 + fq);
    Cst[fq + 0][i] = v.x; Cst[fq + 1][i] = v.y; Cst[fq + 2][i] = v.z; Cst[fq + 3][i] = v.w;
  }
  if (tid < 64) phiT[tid] = Phi[(t0 + tid) * NH + h];

  float acc[4][4] = {};
  for (int sb = 0; sb <= tb; ++sb) {
    const int s0 = sb * 64;
    __syncthreads();  // protect Cst (1st iter) & prior-iter Ss/Xs reads
    // stage B tile (transposed), X tile, per-s scalars
#pragma unroll
    for (int u = 0; u < 4; ++u) {
      int idx = tid + u * 256, i = idx >> 4, fq = (idx & 15) * 4;
      float4 bv = *(const float4*)(proj + (size_t)(s0 + i) * NPROJ + OFF_B + h * 64 + fq);
      Bst[fq + 0][i] = bv.x; Bst[fq + 1][i] = bv.y; Bst[fq + 2][i] = bv.z; Bst[fq + 3][i] = bv.w;
      float4 xv = *(const float4*)(xact + (size_t)(s0 + i) * DINNER + h * HDIM + zh * 64 + fq);
      *(float4*)&Xs[i][fq] = xv;
    }
    if (tid < 64) {
      float p = Phi[(s0 + tid) * NH + h];
      eS[tid] = fminf(-p, 80.f);
      dS[tid] = dts[(s0 + tid) * NH + h];
    }
    __syncthreads();
    // S[i][j] = C_t . B_s over d=0..63 (4x4 per thread, in regs)
    float sreg[4][4] = {};
#pragma unroll 16
    for (int d = 0; d < 64; ++d) {
      float4 cv = *(const float4*)&Cst[d][ri];
      float4 bv = *(const float4*)&Bst[d][cj];
      float a[4] = {cv.x, cv.y, cv.z, cv.w};
      float b[4] = {bv.x, bv.y, bv.z, bv.w};
#pragma unroll
      for (int i = 0; i < 4; ++i)
#pragma unroll
        for (int j = 0; j < 4; ++j) sreg[i][j] = fmaf(a[i], b[j], sreg[i][j]);
    }
    __syncthreads();  // all Bst reads done; safe to overwrite with masked S
#pragma unroll
    for (int i = 0; i < 4; ++i) {
      int ti = t0 + ri + i;
#pragma unroll
      for (int j = 0; j < 4; ++j) {
        int sj = s0 + cj + j;
        float f = (sj <= ti) ? expf(phiT[ri + i] + eS[cj + j]) * dS[cj + j] : 0.f;
        Bst[ri + i][cj + j] = sreg[i][j] * f;
      }
    }
    __syncthreads();
    // Y[i][c] += sum_j S[i][j] * X[j][c]
#pragma unroll 8
    for (int j = 0; j < 64; j += 4) {
      float4 x0 = *(const float4*)&Xs[j + 0][cj];
      float4 x1 = *(const float4*)&Xs[j + 1][cj];
      float4 x2 = *(const float4*)&Xs[j + 2][cj];
      float4 x3 = *(const float4*)&Xs[j + 3][cj];
      float X0[4] = {x0.x, x0.y, x0.z, x0.w};
      float X1[4] = {x1.x, x1.y, x1.z, x1.w};
      float X2[4] = {x2.x, x2.y, x2.z, x2.w};
      float X3[4] = {x3.x, x3.y, x3.z, x3.w};
#pragma unroll
      for (int i = 0; i < 4; ++i) {
        float4 sv = *(const float4*)&Bst[ri + i][j];
#pragma unroll
        for (int c = 0; c < 4; ++c) {
          acc[i][c] = fmaf(sv.x, X0[c], acc[i][c]);
          acc[i][c] = fmaf(sv.y, X1[c], acc[i][c]);
          acc[i][c] = fmaf(sv.z, X2[c], acc[i][c]);
          acc[i][c] = fmaf(sv.w, X3[c], acc[i][c]);
        }
      }
    }
  }
  // epilogue: + Dp * x  (Xs currently holds the tb block's X, since last sb==tb)
  float dp = Dp[h];
#pragma unroll
  for (int i = 0; i < 4; ++i)
#pragma unroll
    for (int j = 0; j < 4; ++j)
      y[(size_t)(t0 + ri + i) * DINNER + h * HDIM + zh * 64 + cj + j] =
          acc[i][j] + dp * Xs[ri + i][cj + j];
}

// ---------------- RMSNorm over 1536 + norm_w + silu(z) gate ----------------
__global__ __launch_bounds__(256) void norm_gate(const float* __restrict__ y,
    const float* __restrict__ proj, const float* __restrict__ nw, float* __restrict__ yn) {
  int t = blockIdx.x, tid = threadIdx.x;
  float v[6], ss = 0.f;
#pragma unroll
  for (int k = 0; k < 6; ++k) {
    v[k] = y[(size_t)t * DINNER + tid + k * 256];
    ss = fmaf(v[k], v[k], ss);
  }
#pragma unroll
  for (int d = 1; d < 64; d <<= 1) ss += __shfl_xor(ss, d);
  __shared__ float wsum[4];
  int wv = tid >> 6;
  if ((tid & 63) == 0) wsum[wv] = ss;
  __syncthreads();
  float tot = wsum[0] + wsum[1] + wsum[2] + wsum[3];
  float rms = rsqrtf(tot / 1536.f + 1e-5f);
#pragma unroll
  for (int k = 0; k < 6; ++k) {
    int c = tid + k * 256;
    float z = proj[(size_t)t * NPROJ + OFF_Z + c];
    float sz = z / (1.f + expf(-z));
    yn[(size_t)t * DINNER + c] = v[k] * rms * nw[c] * sz;
  }
}

extern "C" void kernel_launch(void* const* d_in, const int* in_sizes, int n_in,
                              void* d_out, int out_size, void* d_ws, size_t ws_size,
                              hipStream_t stream) {
  const float* x       = (const float*)d_in[0];
  const float* W_in    = (const float*)d_in[1];
  const float* conv_w  = (const float*)d_in[2];
  const float* conv_b  = (const float*)d_in[3];
  const float* A_log   = (const float*)d_in[4];
  const float* Dp      = (const float*)d_in[5];
  const float* dt_bias = (const float*)d_in[6];
  const float* W_out   = (const float*)d_in[7];
  const float* norm_w  = (const float*)d_in[8];
  float* out = (float*)d_out;

  float* ws   = (float*)d_ws;                    // ~38 MB of f32 scratch
  float* proj = ws;                              // 1024*4620
  float* xact = proj + (size_t)LSEQ * NPROJ;     // 1024*1536
  float* ybuf = xact + (size_t)LSEQ * DINNER;    // 1024*1536
  float* ynb  = ybuf + (size_t)LSEQ * DINNER;    // 1024*1536
  float* Phi  = ynb  + (size_t)LSEQ * DINNER;    // 1024*12
  float* dtsb = Phi  + (size_t)LSEQ * NH;        // 1024*12

  // 1. in-projection: proj = x @ W_in^T   (1024x768 @ 768x4620)
  gemm_abt<<<dim3((NPROJ + 63) / 64, LSEQ / 64), 256, 0, stream>>>(
      x, W_in, proj, LSEQ, NPROJ, 768);
  // 2. conv + silu -> xact
  conv_silu<<<dim3(LSEQ * DINNER / 256), 256, 0, stream>>>(proj, conv_w, conv_b, xact);
  // 3. dt & Phi cumsum
  dtphi<<<dim3(NH), 256, 0, stream>>>(proj, A_log, dt_bias, Phi, dtsb);
  // 4. SSM via masked quadratic form -> ybuf
  ssm_quad<<<dim3(LSEQ / 64, NH, 2), 256, 0, stream>>>(proj, xact, Phi, dtsb, Dp, ybuf);
  // 5. RMSNorm + gate -> ynb
  norm_gate<<<dim3(LSEQ), 256, 0, stream>>>(ybuf, proj, norm_w, ynb);
  // 6. out-projection: out = ynb @ W_out^T  (1024x1536 @ 1536x768)
  gemm_abt<<<dim3(768 / 64, LSEQ / 64), 256, 0, stream>>>(ynb, W_out, out, LSEQ, 768, DINNER);
}

// Round 2
// 132.153 us; speedup vs baseline: 2.8456x; 2.8456x over previous
//
#include <hip/hip_runtime.h>
#include <cmath>

#define LSEQ   1024
#define NPROJ  4620
#define NPAD   4736
#define DINNER 1536
#define NH     12
#define HDIM   128
#define OFF_Z  0
#define OFF_X  1536
#define OFF_B  3072
#define OFF_C  3840
#define OFF_DT 4608

typedef unsigned short u16;
typedef short bf16x8 __attribute__((ext_vector_type(8)));
typedef float f32x4 __attribute__((ext_vector_type(4)));

__device__ inline u16 f2b(float f) {            // f32 -> bf16 RNE
  unsigned u = __float_as_uint(f);
  return (u16)((u + 0x7fffu + ((u >> 16) & 1u)) >> 16);
}
__device__ inline float b2f(u16 h) { return __uint_as_float(((unsigned)h) << 16); }

__device__ inline void gll16(const void* g, void* l) {
  __builtin_amdgcn_global_load_lds((const __attribute__((address_space(1))) void*)g,
                                   (__attribute__((address_space(3))) void*)l, 16, 0, 0);
}

// ---------- split f32 -> (hi,lo) bf16 planes; zero-pad beyond nsrc ----------
__global__ __launch_bounds__(256) void ksplit(const float* __restrict__ s,
    u16* __restrict__ hi, u16* __restrict__ lo, int nsrc4, int ntot4) {
  int i = blockIdx.x * 256 + threadIdx.x;
  if (i >= ntot4) return;
  float4 v = (i < nsrc4) ? ((const float4*)s)[i] : make_float4(0.f, 0.f, 0.f, 0.f);
  float a[4] = {v.x, v.y, v.z, v.w};
  u16 h[4], l[4];
#pragma unroll
  for (int j = 0; j < 4; ++j) {
    h[j] = f2b(a[j]);
    l[j] = f2b(a[j] - b2f(h[j]));
  }
  uint2 hp, lp;
  hp.x = (unsigned)h[0] | ((unsigned)h[1] << 16); hp.y = (unsigned)h[2] | ((unsigned)h[3] << 16);
  lp.x = (unsigned)l[0] | ((unsigned)l[1] << 16); lp.y = (unsigned)l[2] | ((unsigned)l[3] << 16);
  ((uint2*)hi)[i] = hp;
  ((uint2*)lo)[i] = lp;
}

// ---------- bf16x3 MFMA GEMM: C[M,N] = A[M,K] * W[N,K]^T  (hi/lo planes) ----
// BT x BT tile, BK=32, 4 waves (2x2), FR = BT/32 fragments per wave dim.
template<int BT, int FR, bool NG>
__global__ __launch_bounds__(256) void gemm3(const u16* __restrict__ Ah,
    const u16* __restrict__ Al, const u16* __restrict__ Wh, const u16* __restrict__ Wl,
    float* __restrict__ C, int Kdim, int Nreal, int ldc) {
  __shared__ u16 lds[2][4][BT * 32];
  const int tid = threadIdx.x;
  const int l = tid & 63, w = tid >> 6;
  const int m0 = blockIdx.y * BT, n0 = blockIdx.x * BT;
  const int HB = BT / 2;
  const int wm = w >> 1, wn = w & 1;
  const int kg = l >> 4, li = l & 15;

  const u16* gbase; int r0;
  if (w == 0)      { gbase = Ah; r0 = m0; }
  else if (w == 1) { gbase = Al; r0 = m0; }
  else if (w == 2) { gbase = Wh; r0 = n0; }
  else             { gbase = Wl; r0 = n0; }

  auto stage = [&](int buf, int t) {
    const int k0 = t * 32;
#pragma unroll
    for (int i = 0; i < BT / 16; ++i) {
      int row = i * 16 + (l >> 2);
      int slotg = (l & 3) ^ ((row >> 1) & 3);
      const u16* gp = gbase + (size_t)(r0 + row) * Kdim + k0 + slotg * 8;
      gll16(gp, &lds[buf][w][i * 512]);
    }
  };
  auto frag = [&](int buf, int p, int row) -> bf16x8 {
    int off = row * 32 + ((kg ^ ((row >> 1) & 3)) << 3);
    return *(const bf16x8*)&lds[buf][p][off];
  };

  f32x4 acc[FR][FR];
#pragma unroll
  for (int m = 0; m < FR; ++m)
#pragma unroll
    for (int n = 0; n < FR; ++n) acc[m][n] = (f32x4){0.f, 0.f, 0.f, 0.f};

  const int NT = Kdim / 32;
  stage(0, 0);
  asm volatile("s_waitcnt vmcnt(0)" ::: "memory");
  __syncthreads();
  for (int t = 0; t < NT; ++t) {
    const int buf = t & 1;
    if (t + 1 < NT) stage(buf ^ 1, t + 1);
    bf16x8 af[FR][2], wf[FR][2];
#pragma unroll
    for (int m = 0; m < FR; ++m) {
      int row = wm * HB + m * 16 + li;
      af[m][0] = frag(buf, 0, row);
      af[m][1] = frag(buf, 1, row);
    }
#pragma unroll
    for (int n = 0; n < FR; ++n) {
      int row = wn * HB + n * 16 + li;
      wf[n][0] = frag(buf, 2, row);
      wf[n][1] = frag(buf, 3, row);
    }
#pragma unroll
    for (int m = 0; m < FR; ++m)
#pragma unroll
      for (int n = 0; n < FR; ++n) {
        acc[m][n] = __builtin_amdgcn_mfma_f32_16x16x32_bf16(af[m][0], wf[n][0], acc[m][n], 0, 0, 0);
        acc[m][n] = __builtin_amdgcn_mfma_f32_16x16x32_bf16(af[m][0], wf[n][1], acc[m][n], 0, 0, 0);
        acc[m][n] = __builtin_amdgcn_mfma_f32_16x16x32_bf16(af[m][1], wf[n][0], acc[m][n], 0, 0, 0);
      }
    asm volatile("s_waitcnt vmcnt(0)" ::: "memory");
    __syncthreads();
  }
#pragma unroll
  for (int m = 0; m < FR; ++m) {
    int rbase = m0 + wm * HB + m * 16 + kg * 4;
#pragma unroll
    for (int n = 0; n < FR; ++n) {
      int col = n0 + wn * HB + n * 16 + li;
      if (!NG || col < Nreal) {
#pragma unroll
        for (int r = 0; r < 4; ++r)
          C[(size_t)(rbase + r) * ldc + col] = acc[m][n][r];
      }
    }
  }
}

// ---------------- conv1d (depthwise, kernel 4, causal) + SiLU ----------------
__global__ __launch_bounds__(256) void conv_silu(const float* __restrict__ proj,
    const float* __restrict__ cw, const float* __restrict__ cb, float* __restrict__ xact) {
  int idx = blockIdx.x * 256 + threadIdx.x;
  int c = idx % DINNER, t = idx / DINNER;
  float a = cb[c];
#pragma unroll
  for (int i = 0; i < 4; ++i) {
    int tt = t + i - 3;
    if (tt >= 0) a = fmaf(proj[(size_t)tt * NPROJ + OFF_X + c], cw[c * 4 + i], a);
  }
  xact[idx] = a / (1.f + expf(-a));
}

// ---------------- dt = softplus(dt_r)+bias ; Phi = cumsum(A*dt) --------------
__global__ __launch_bounds__(256) void dtphi(const float* __restrict__ proj,
    const float* __restrict__ A_log, const float* __restrict__ dt_bias,
    float* __restrict__ Phi, float* __restrict__ dts) {
  int h = blockIdx.x, tid = threadIdx.x;
  float Ac = -expf(A_log[h]);
  float bb = dt_bias[h];
  float v[4], s = 0.f;
#pragma unroll
  for (int u = 0; u < 4; ++u) {
    int t = tid * 4 + u;
    float xr = proj[(size_t)t * NPROJ + OFF_DT + h];
    float sp = (xr > 20.f) ? xr : log1pf(expf(xr));
    v[u] = sp + bb;
    s += v[u];
  }
  int lane = tid & 63, wv = tid >> 6;
  float ps = s;
#pragma unroll
  for (int d = 1; d < 64; d <<= 1) {
    float o = __shfl_up(ps, d);
    if (lane >= d) ps += o;
  }
  __shared__ float wsum[4];
  if (lane == 63) wsum[wv] = ps;
  __syncthreads();
  float off = 0.f;
  for (int w = 0; w < wv; ++w) off += wsum[w];
  float run = off + ps - s;
#pragma unroll
  for (int u = 0; u < 4; ++u) {
    int t = tid * 4 + u;
    run += v[u];
    Phi[t * NH + h] = Ac * run;
    dts[t * NH + h] = v[u];
  }
}

// ---------------- chunk-local state: Sloc[k,h] = sum_s w_s * B_s (x) dtx_s ----
__global__ __launch_bounds__(256) void chunk_state(const float* __restrict__ proj,
    const float* __restrict__ xact, const float* __restrict__ Phi,
    const float* __restrict__ dts, float* __restrict__ Sloc) {
  const int k = blockIdx.x, h = blockIdx.y, tid = threadIdx.x;
  __shared__ float Bw[64][68];
  __shared__ float Xs[64][132];
  __shared__ float wS[64];
  const int s0 = k * 64;
  if (tid < 64) {
    float pe = Phi[(s0 + 63) * NH + h];
    float p  = Phi[(s0 + tid) * NH + h];
    wS[tid] = expf(pe + fminf(-p, 80.f)) * dts[(s0 + tid) * NH + h];
  }
  __syncthreads();
#pragma unroll
  for (int u = 0; u < 4; ++u) {
    int idx = tid + u * 256, s = idx >> 4, q = (idx & 15) * 4;
    float4 v = *(const float4*)(proj + (size_t)(s0 + s) * NPROJ + OFF_B + h * 64 + q);
    float ws_ = wS[s];
    Bw[s][q + 0] = v.x * ws_; Bw[s][q + 1] = v.y * ws_;
    Bw[s][q + 2] = v.z * ws_; Bw[s][q + 3] = v.w * ws_;
  }
#pragma unroll
  for (int u = 0; u < 8; ++u) {
    int idx = tid + u * 256, s = idx >> 5, q = (idx & 31) * 4;
    *(float4*)&Xs[s][q] = *(const float4*)(xact + (size_t)(s0 + s) * DINNER + h * HDIM + q);
  }
  __syncthreads();
  const int d0 = (tid >> 4) * 4, c0 = (tid & 15) * 8;
  float acc[4][8] = {};
#pragma unroll 8
  for (int s = 0; s < 64; ++s) {
    float4 b  = *(const float4*)&Bw[s][d0];
    float4 xa = *(const float4*)&Xs[s][c0];
    float4 xb = *(const float4*)&Xs[s][c0 + 4];
    float bb[4] = {b.x, b.y, b.z, b.w};
    float xx[8] = {xa.x, xa.y, xa.z, xa.w, xb.x, xb.y, xb.z, xb.w};
#pragma unroll
    for (int i = 0; i < 4; ++i)
#pragma unroll
      for (int j = 0; j < 8; ++j) acc[i][j] = fmaf(bb[i], xx[j], acc[i][j]);
  }
  float* dst = Sloc + ((size_t)(k * NH + h) << 13);
#pragma unroll
  for (int i = 0; i < 4; ++i) {
    *(float4*)(dst + (d0 + i) * 128 + c0)     = make_float4(acc[i][0], acc[i][1], acc[i][2], acc[i][3]);
    *(float4*)(dst + (d0 + i) * 128 + c0 + 4) = make_float4(acc[i][4], acc[i][5], acc[i][6], acc[i][7]);
  }
}

// ---------------- sequential scan over 16 chunks (inclusive states) ----------
__global__ __launch_bounds__(256) void chunk_scan(float* __restrict__ Sloc,
    const float* __restrict__ Phi) {
  int b = blockIdx.x;
  int h = b >> 5;
  int e = (b & 31) * 256 + threadIdx.x;
  float run = Sloc[((size_t)h << 13) + e];
#pragma unroll
  for (int k = 1; k < 16; ++k) {
    float lam = expf(Phi[(k * 64 + 63) * NH + h] - Phi[(k * 64 - 1) * NH + h]);
    size_t o = ((size_t)(k * NH + h) << 13) + e;
    run = fmaf(lam, run, Sloc[o]);
    Sloc[o] = run;
  }
}

// ---------------- per-chunk output: diag quadratic + carried state + Dp*x ----
__global__ __launch_bounds__(256) void ssm_out(const float* __restrict__ proj,
    const float* __restrict__ xact, const float* __restrict__ Phi,
    const float* __restrict__ dts, const float* __restrict__ Dp,
    const float* __restrict__ Sloc, float* __restrict__ y) {
  const int k = blockIdx.x, h = blockIdx.y, zh = blockIdx.z, tid = threadIdx.x;
  __shared__ float Cst[64][68];   // [d][t]
  __shared__ float Bst[64][68];   // [d][s]; later masked S[t][s]
  __shared__ float Xs[64][68];    // [s][c]; later Sprev[d][c]
  __shared__ float phiT[64], eS[64], dS[64], eT[64];
  const int t0 = k * 64;
  const int ty = tid >> 4, tx = tid & 15, ri = ty * 4, cj = tx * 4;

#pragma unroll
  for (int u = 0; u < 4; ++u) {
    int idx = tid + u * 256, i = idx >> 4, fq = (idx & 15) * 4;
    float4 cv = *(const float4*)(proj + (size_t)(t0 + i) * NPROJ + OFF_C + h * 64 + fq);
    Cst[fq + 0][i] = cv.x; Cst[fq + 1][i] = cv.y; Cst[fq + 2][i] = cv.z; Cst[fq + 3][i] = cv.w;
    float4 bv = *(const float4*)(proj + (size_t)(t0 + i) * NPROJ + OFF_B + h * 64 + fq);
    Bst[fq + 0][i] = bv.x; Bst[fq + 1][i] = bv.y; Bst[fq + 2][i] = bv.z; Bst[fq + 3][i] = bv.w;
    float4 xv = *(const float4*)(xact + (size_t)(t0 + i) * DINNER + h * HDIM + zh * 64 + fq);
    *(float4*)&Xs[i][fq] = xv;
  }
  if (tid < 64) {
    float p = Phi[(t0 + tid) * NH + h];
    phiT[tid] = p;
    eS[tid] = fminf(-p, 80.f);
    dS[tid] = dts[(t0 + tid) * NH + h];
    eT[tid] = (k > 0) ? expf(p - Phi[(t0 - 1) * NH + h]) : 0.f;
  }
  __syncthreads();

  // S-diag = C_t . B_s
  float sreg[4][4] = {};
#pragma unroll 16
  for (int d = 0; d < 64; ++d) {
    float4 cv = *(const float4*)&Cst[d][ri];
    float4 bv = *(const float4*)&Bst[d][cj];
    float a[4] = {cv.x, cv.y, cv.z, cv.w};
    float b[4] = {bv.x, bv.y, bv.z, bv.w};
#pragma unroll
    for (int i = 0; i < 4; ++i)
#pragma unroll
      for (int j = 0; j < 4; ++j) sreg[i][j] = fmaf(a[i], b[j], sreg[i][j]);
  }
  __syncthreads();
#pragma unroll
  for (int i = 0; i < 4; ++i) {
    int ti = ri + i;
#pragma unroll
    for (int j = 0; j < 4; ++j) {
      int sj = cj + j;
      float f = (sj <= ti) ? expf(phiT[ti] + eS[sj]) * dS[sj] : 0.f;
      Bst[ti][sj] = sreg[i][j] * f;
    }
  }
  __syncthreads();

  // PV-diag
  float acc[4][4] = {};
#pragma unroll 8
  for (int j = 0; j < 64; j += 4) {
    float4 x0 = *(const float4*)&Xs[j + 0][cj];
    float4 x1 = *(const float4*)&Xs[j + 1][cj];
    float4 x2 = *(const float4*)&Xs[j + 2][cj];
    float4 x3 = *(const float4*)&Xs[j + 3][cj];
    float X0[4] = {x0.x, x0.y, x0.z, x0.w};
    float X1[4] = {x1.x, x1.y, x1.z, x1.w};
    float X2[4] = {x2.x, x2.y, x2.z, x2.w};
    float X3[4] = {x3.x, x3.y, x3.z, x3.w};
#pragma unroll
    for (int i = 0; i < 4; ++i) {
      float4 sv = *(const float4*)&Bst[ri + i][j];
#pragma unroll
      for (int c = 0; c < 4; ++c) {
        acc[i][c] = fmaf(sv.x, X0[c], acc[i][c]);
        acc[i][c] = fmaf(sv.y, X1[c], acc[i][c]);
        acc[i][c] = fmaf(sv.z, X2[c], acc[i][c]);
        acc[i][c] = fmaf(sv.w, X3[c], acc[i][c]);
      }
    }
  }
  // + Dp * x (Xs still holds this chunk's X)
  float dp = Dp[h];
#pragma unroll
  for (int i = 0; i < 4; ++i)
#pragma unroll
    for (int j = 0; j < 4; ++j) acc[i][j] = fmaf(dp, Xs[ri + i][cj + j], acc[i][j]);

  if (k > 0) {
    __syncthreads();
#pragma unroll
    for (int u = 0; u < 4; ++u) {
      int idx = tid + u * 256, d = idx >> 4, q = (idx & 15) * 4;
      *(float4*)&Xs[d][q] =
          *(const float4*)(Sloc + ((size_t)((k - 1) * NH + h) << 13) + d * 128 + zh * 64 + q);
    }
    __syncthreads();
    float a2[4][4] = {};
#pragma unroll 16
    for (int d = 0; d < 64; ++d) {
      float4 cv = *(const float4*)&Cst[d][ri];
      float4 sv = *(const float4*)&Xs[d][cj];
      float a[4] = {cv.x, cv.y, cv.z, cv.w};
      float b[4] = {sv.x, sv.y, sv.z, sv.w};
#pragma unroll
      for (int i = 0; i < 4; ++i)
#pragma unroll
        for (int j = 0; j < 4; ++j) a2[i][j] = fmaf(a[i], b[j], a2[i][j]);
    }
#pragma unroll
    for (int i = 0; i < 4; ++i)
#pragma unroll
      for (int j = 0; j < 4; ++j) acc[i][j] = fmaf(eT[ri + i], a2[i][j], acc[i][j]);
  }
#pragma unroll
  for (int i = 0; i < 4; ++i)
    *(float4*)(y + (size_t)(t0 + ri + i) * DINNER + h * HDIM + zh * 64 + cj) =
        make_float4(acc[i][0], acc[i][1], acc[i][2], acc[i][3]);
}

// ---------------- RMSNorm + gate -> split bf16 planes ----------------
__global__ __launch_bounds__(256) void norm_gate(const float* __restrict__ y,
    const float* __restrict__ proj, const float* __restrict__ nw,
    u16* __restrict__ yh, u16* __restrict__ yl) {
  int t = blockIdx.x, tid = threadIdx.x;
  float v[6], ss = 0.f;
#pragma unroll
  for (int k = 0; k < 6; ++k) {
    v[k] = y[(size_t)t * DINNER + tid + k * 256];
    ss = fmaf(v[k], v[k], ss);
  }
#pragma unroll
  for (int d = 1; d < 64; d <<= 1) ss += __shfl_xor(ss, d);
  __shared__ float wsum[4];
  int wv = tid >> 6;
  if ((tid & 63) == 0) wsum[wv] = ss;
  __syncthreads();
  float tot = wsum[0] + wsum[1] + wsum[2] + wsum[3];
  float rms = rsqrtf(tot / 1536.f + 1e-5f);
#pragma unroll
  for (int k = 0; k < 6; ++k) {
    int c = tid + k * 256;
    float z = proj[(size_t)t * NPROJ + OFF_Z + c];
    float sz = z / (1.f + expf(-z));
    float val = v[k] * rms * nw[c] * sz;
    u16 hh = f2b(val);
    yh[(size_t)t * DINNER + c] = hh;
    yl[(size_t)t * DINNER + c] = f2b(val - b2f(hh));
  }
}

extern "C" void kernel_launch(void* const* d_in, const int* in_sizes, int n_in,
                              void* d_out, int out_size, void* d_ws, size_t ws_size,
                              hipStream_t stream) {
  const float* x       = (const float*)d_in[0];
  const float* W_in    = (const float*)d_in[1];
  const float* conv_w  = (const float*)d_in[2];
  const float* conv_b  = (const float*)d_in[3];
  const float* A_log   = (const float*)d_in[4];
  const float* Dp      = (const float*)d_in[5];
  const float* dt_bias = (const float*)d_in[6];
  const float* W_out   = (const float*)d_in[7];
  const float* norm_w  = (const float*)d_in[8];
  float* out = (float*)d_out;

  char* base = (char*)d_ws;
  size_t o = 0;
  auto alloc = [&](size_t bytes) { char* r = base + o; o += (bytes + 255) & ~(size_t)255; return r; };
  float* proj = (float*)alloc((size_t)LSEQ * NPROJ * 4);
  float* xact = (float*)alloc((size_t)LSEQ * DINNER * 4);
  float* ybuf = (float*)alloc((size_t)LSEQ * DINNER * 4);
  float* Phi  = (float*)alloc((size_t)LSEQ * NH * 4);
  float* dtsb = (float*)alloc((size_t)LSEQ * NH * 4);
  float* Sloc = (float*)alloc((size_t)16 * NH * 64 * 128 * 4);
  u16* Ahi  = (u16*)alloc((size_t)LSEQ * 768 * 2);
  u16* Alo  = (u16*)alloc((size_t)LSEQ * 768 * 2);
  u16* Whi  = (u16*)alloc((size_t)NPAD * 768 * 2);
  u16* Wlo  = (u16*)alloc((size_t)NPAD * 768 * 2);
  u16* Wohi = (u16*)alloc((size_t)768 * DINNER * 2);
  u16* Wolo = (u16*)alloc((size_t)768 * DINNER * 2);
  u16* Yh   = (u16*)alloc((size_t)LSEQ * DINNER * 2);
  u16* Yl   = (u16*)alloc((size_t)LSEQ * DINNER * 2);

  // splits
  {
    int n4 = LSEQ * 768 / 4;
    ksplit<<<dim3((n4 + 255) / 256), 256, 0, stream>>>(x, Ahi, Alo, n4, n4);
  }
  {
    int ns4 = NPROJ * 768 / 4, nt4 = NPAD * 768 / 4;
    ksplit<<<dim3((nt4 + 255) / 256), 256, 0, stream>>>(W_in, Whi, Wlo, ns4, nt4);
  }
  {
    int n4 = 768 * DINNER / 4;
    ksplit<<<dim3((n4 + 255) / 256), 256, 0, stream>>>(W_out, Wohi, Wolo, n4, n4);
  }
  // in-projection (bf16x3 MFMA)
  gemm3<128, 4, true><<<dim3(NPAD / 128, LSEQ / 128), 256, 0, stream>>>(
      Ahi, Alo, Whi, Wlo, proj, 768, NPROJ, NPROJ);
  // conv + silu
  conv_silu<<<dim3(LSEQ * DINNER / 256), 256, 0, stream>>>(proj, conv_w, conv_b, xact);
  // dt & Phi
  dtphi<<<dim3(NH), 256, 0, stream>>>(proj, A_log, dt_bias, Phi, dtsb);
  // chunked SSM
  chunk_state<<<dim3(16, NH), 256, 0, stream>>>(proj, xact, Phi, dtsb, Sloc);
  chunk_scan<<<dim3(NH * 32), 256, 0, stream>>>(Sloc, Phi);
  ssm_out<<<dim3(16, NH, 2), 256, 0, stream>>>(proj, xact, Phi, dtsb, Dp, Sloc, ybuf);
  // norm + gate -> split planes
  norm_gate<<<dim3(LSEQ), 256, 0, stream>>>(ybuf, proj, norm_w, Yh, Yl);
  // out-projection (bf16x3 MFMA)
  gemm3<64, 2, false><<<dim3(768 / 64, LSEQ / 64), 256, 0, stream>>>(
      Yh, Yl, Wohi, Wolo, out, DINNER, 768, 768);
}

// Round 3
// 117.426 us; speedup vs baseline: 3.2025x; 1.1254x over previous
//
#include <hip/hip_runtime.h>
#include <cmath>

#define LSEQ   1024
#define NPROJ  4620
#define NPAD   5120
#define DINNER 1536
#define NH     12
#define HDIM   128
#define OFF_Z  0
#define OFF_X  1536
#define OFF_B  3072
#define OFF_C  3840
#define OFF_DT 4608

typedef unsigned short u16;
typedef short bf16x8 __attribute__((ext_vector_type(8)));
typedef float f32x4 __attribute__((ext_vector_type(4)));

__device__ inline u16 f2b(float f) {            // f32 -> bf16 RNE
  unsigned u = __float_as_uint(f);
  return (u16)((u + 0x7fffu + ((u >> 16) & 1u)) >> 16);
}
__device__ inline float b2f(u16 h) { return __uint_as_float(((unsigned)h) << 16); }

__device__ inline void gll16(const void* g, void* l) {
  __builtin_amdgcn_global_load_lds((const __attribute__((address_space(1))) void*)g,
                                   (__attribute__((address_space(3))) void*)l, 16, 0, 0);
}

// ---------- merged split f32 -> (hi,lo) bf16 planes for x, W_in(pad), W_out ----
#define S0N 196608              // 1024*768/4
#define S1N 983040              // 5120*768/4  (src valid 887040)
#define S1V 887040              // 4620*768/4
#define S2N 294912              // 768*1536/4
__global__ __launch_bounds__(256) void ksplit_all(const float* __restrict__ x,
    const float* __restrict__ Wi, const float* __restrict__ Wo,
    u16* __restrict__ Ahi, u16* __restrict__ Alo, u16* __restrict__ Whi,
    u16* __restrict__ Wlo, u16* __restrict__ Wohi, u16* __restrict__ Wolo) {
  int i = blockIdx.x * 256 + threadIdx.x;
  const float* src; u16 *hi, *lo; int j, valid;
  if (i < S0N)            { src = x;  hi = Ahi;  lo = Alo;  j = i;              valid = S0N; }
  else if (i < S0N + S1N) { src = Wi; hi = Whi;  lo = Wlo;  j = i - S0N;        valid = S1V; }
  else                    { src = Wo; hi = Wohi; lo = Wolo; j = i - S0N - S1N;  valid = S2N; }
  float4 v = (j < valid) ? ((const float4*)src)[j] : make_float4(0.f, 0.f, 0.f, 0.f);
  float a[4] = {v.x, v.y, v.z, v.w};
  u16 h[4], l[4];
#pragma unroll
  for (int q = 0; q < 4; ++q) { h[q] = f2b(a[q]); l[q] = f2b(a[q] - b2f(h[q])); }
  uint2 hp, lp;
  hp.x = (unsigned)h[0] | ((unsigned)h[1] << 16); hp.y = (unsigned)h[2] | ((unsigned)h[3] << 16);
  lp.x = (unsigned)l[0] | ((unsigned)l[1] << 16); lp.y = (unsigned)l[2] | ((unsigned)l[3] << 16);
  ((uint2*)hi)[j] = hp;
  ((uint2*)lo)[j] = lp;
}

// ---------- bf16x3 MFMA GEMM: C[M,N] = A[M,K] * W[N,K]^T  (hi/lo planes) ----
// BM x BN tile, BK=32, 4 waves (2x2). MAP0: in-proj XCD stripes (640 blocks).
// MAP1: out-proj split-K=2 with XCD grouping (384 blocks).
template<int BM, int BN, int MAP, bool NG>
__global__ __launch_bounds__(256) void gemm3(const u16* __restrict__ Ah,
    const u16* __restrict__ Al, const u16* __restrict__ Wh, const u16* __restrict__ Wl,
    float* __restrict__ C, int lda, int ldw, int Ksl, int Nreal, int ldc) {
  constexpr int FRm = BM / 32, FRn = BN / 32;
  constexpr int PA = BM * 32, PW = BN * 32;
  constexpr int PB = 2 * PA + 2 * PW;            // u16 per buffer
  __shared__ u16 lds[2 * PB];
  const int tid = threadIdx.x;
  const int l = tid & 63, w = tid >> 6;
  const int wm = w >> 1, wn = w & 1;
  const int kg = l >> 4, li = l & 15;

  int b = blockIdx.x, m0, n0, koff;
  float* Cp = C;
  if (MAP == 0) {                 // 8 xcd * (5 colblk(128) x 16 rowblk(64))
    int xcd = b & 7, idx = b >> 3;
    m0 = (idx & 15) * 64;
    n0 = (xcd * 5 + (idx >> 4)) * 128;
    koff = 0;
  } else {                        // 8 xcd * (3 grp x 16 rowblk); grp=(col,kslice)
    int xcd = b & 7, idx = b >> 3;
    int g = xcd * 3 + (idx >> 4);
    m0 = (idx & 15) * 64;
    n0 = (g >> 1) * 64;
    koff = (g & 1) * 768;
    Cp = C + (size_t)(g & 1) * LSEQ * ldc;
  }

  const int poff = (w == 0) ? 0 : (w == 1) ? PA : (w == 2) ? 2 * PA : 2 * PA + PW;
  const u16* gbase = (w == 0) ? Ah : (w == 1) ? Al : (w == 2) ? Wh : Wl;
  const int r0 = (w < 2) ? m0 : n0;
  const int ld = (w < 2) ? lda : ldw;
  constexpr int NRA = BM / 16, NRW = BN / 16;
  const int nrows = (w < 2) ? NRA : NRW;

  auto stage = [&](int buf, int t) {
    const int k0 = koff + t * 32;
    for (int i = 0; i < nrows; ++i) {
      int row = i * 16 + (l >> 2);
      int slotg = (l & 3) ^ ((row >> 1) & 3);
      gll16(gbase + (size_t)(r0 + row) * ld + k0 + slotg * 8,
            &lds[buf * PB + poff + i * 512]);
    }
  };
  auto frag = [&](int buf, int pofr, int row) -> bf16x8 {
    int off = buf * PB + pofr + row * 32 + ((kg ^ ((row >> 1) & 3)) << 3);
    return *(const bf16x8*)&lds[off];
  };

  f32x4 acc[FRm][FRn];
#pragma unroll
  for (int m = 0; m < FRm; ++m)
#pragma unroll
    for (int n = 0; n < FRn; ++n) acc[m][n] = (f32x4){0.f, 0.f, 0.f, 0.f};

  const int NT = Ksl / 32;
  stage(0, 0);
  asm volatile("s_waitcnt vmcnt(0)" ::: "memory");
  __syncthreads();
  for (int t = 0; t < NT; ++t) {
    const int buf = t & 1;
    if (t + 1 < NT) stage(buf ^ 1, t + 1);
    bf16x8 af[FRm][2], wf[FRn][2];
#pragma unroll
    for (int m = 0; m < FRm; ++m) {
      int row = wm * (BM / 2) + m * 16 + li;
      af[m][0] = frag(buf, 0, row);
      af[m][1] = frag(buf, PA, row);
    }
#pragma unroll
    for (int n = 0; n < FRn; ++n) {
      int row = wn * (BN / 2) + n * 16 + li;
      wf[n][0] = frag(buf, 2 * PA, row);
      wf[n][1] = frag(buf, 2 * PA + PW, row);
    }
#pragma unroll
    for (int m = 0; m < FRm; ++m)
#pragma unroll
      for (int n = 0; n < FRn; ++n) {
        acc[m][n] = __builtin_amdgcn_mfma_f32_16x16x32_bf16(af[m][0], wf[n][0], acc[m][n], 0, 0, 0);
        acc[m][n] = __builtin_amdgcn_mfma_f32_16x16x32_bf16(af[m][0], wf[n][1], acc[m][n], 0, 0, 0);
        acc[m][n] = __builtin_amdgcn_mfma_f32_16x16x32_bf16(af[m][1], wf[n][0], acc[m][n], 0, 0, 0);
      }
    asm volatile("s_waitcnt vmcnt(0)" ::: "memory");
    __syncthreads();
  }
#pragma unroll
  for (int m = 0; m < FRm; ++m) {
    int rbase = m0 + wm * (BM / 2) + m * 16 + kg * 4;
#pragma unroll
    for (int n = 0; n < FRn; ++n) {
      int col = n0 + wn * (BN / 2) + n * 16 + li;
      if (!NG || col < Nreal) {
#pragma unroll
        for (int r = 0; r < 4; ++r)
          Cp[(size_t)(rbase + r) * ldc + col] = acc[m][n][r];
      }
    }
  }
}

// ---------------- out = P0 + P1 (split-K reduce) ----------------
__global__ __launch_bounds__(256) void addk(const float* __restrict__ P,
    float* __restrict__ out) {
  int i = blockIdx.x * 256 + threadIdx.x;   // over 1024*768/4
  float4 a = ((const float4*)P)[i];
  float4 b = ((const float4*)(P + (size_t)LSEQ * 768))[i];
  ((float4*)out)[i] = make_float4(a.x + b.x, a.y + b.y, a.z + b.z, a.w + b.w);
}

// ---------------- conv1d (depthwise, kernel 4, causal) + SiLU ----------------
__global__ __launch_bounds__(256) void conv_silu(const float* __restrict__ proj,
    const float* __restrict__ cw, const float* __restrict__ cb, float* __restrict__ xact) {
  int idx = blockIdx.x * 256 + threadIdx.x;
  int c = idx % DINNER, t = idx / DINNER;
  float a = cb[c];
#pragma unroll
  for (int i = 0; i < 4; ++i) {
    int tt = t + i - 3;
    if (tt >= 0) a = fmaf(proj[(size_t)tt * NPROJ + OFF_X + c], cw[c * 4 + i], a);
  }
  xact[idx] = a / (1.f + expf(-a));
}

// ---------------- dt = softplus(dt_r)+bias ; Phi = cumsum(A*dt) --------------
__global__ __launch_bounds__(256) void dtphi(const float* __restrict__ proj,
    const float* __restrict__ A_log, const float* __restrict__ dt_bias,
    float* __restrict__ Phi, float* __restrict__ dts) {
  int h = blockIdx.x, tid = threadIdx.x;
  float Ac = -expf(A_log[h]);
  float bb = dt_bias[h];
  float v[4], s = 0.f;
#pragma unroll
  for (int u = 0; u < 4; ++u) {
    int t = tid * 4 + u;
    float xr = proj[(size_t)t * NPROJ + OFF_DT + h];
    float sp = (xr > 20.f) ? xr : log1pf(expf(xr));
    v[u] = sp + bb;
    s += v[u];
  }
  int lane = tid & 63, wv = tid >> 6;
  float ps = s;
#pragma unroll
  for (int d = 1; d < 64; d <<= 1) {
    float o = __shfl_up(ps, d);
    if (lane >= d) ps += o;
  }
  __shared__ float wsum[4];
  if (lane == 63) wsum[wv] = ps;
  __syncthreads();
  float off = 0.f;
  for (int w = 0; w < wv; ++w) off += wsum[w];
  float run = off + ps - s;
#pragma unroll
  for (int u = 0; u < 4; ++u) {
    int t = tid * 4 + u;
    run += v[u];
    Phi[t * NH + h] = Ac * run;
    dts[t * NH + h] = v[u];
  }
}

// ---------------- chunk-local state: Sloc[k,h] = sum_s w_s * B_s (x) x_s ----
__global__ __launch_bounds__(256) void chunk_state(const float* __restrict__ proj,
    const float* __restrict__ xact, const float* __restrict__ Phi,
    const float* __restrict__ dts, float* __restrict__ Sloc) {
  const int k = blockIdx.x, h = blockIdx.y, tid = threadIdx.x;
  __shared__ float Bw[64][68];
  __shared__ float Xs[64][132];
  __shared__ float wS[64];
  const int s0 = k * 64;
  if (tid < 64) {
    float pe = Phi[(s0 + 63) * NH + h];
    float p  = Phi[(s0 + tid) * NH + h];
    wS[tid] = expf(pe + fminf(-p, 80.f)) * dts[(s0 + tid) * NH + h];
  }
  __syncthreads();
#pragma unroll
  for (int u = 0; u < 4; ++u) {
    int idx = tid + u * 256, s = idx >> 4, q = (idx & 15) * 4;
    float4 v = *(const float4*)(proj + (size_t)(s0 + s) * NPROJ + OFF_B + h * 64 + q);
    float ws_ = wS[s];
    Bw[s][q + 0] = v.x * ws_; Bw[s][q + 1] = v.y * ws_;
    Bw[s][q + 2] = v.z * ws_; Bw[s][q + 3] = v.w * ws_;
  }
#pragma unroll
  for (int u = 0; u < 8; ++u) {
    int idx = tid + u * 256, s = idx >> 5, q = (idx & 31) * 4;
    *(float4*)&Xs[s][q] = *(const float4*)(xact + (size_t)(s0 + s) * DINNER + h * HDIM + q);
  }
  __syncthreads();
  const int d0 = (tid >> 4) * 4, c0 = (tid & 15) * 8;
  float acc[4][8] = {};
#pragma unroll 8
  for (int s = 0; s < 64; ++s) {
    float4 b  = *(const float4*)&Bw[s][d0];
    float4 xa = *(const float4*)&Xs[s][c0];
    float4 xb = *(const float4*)&Xs[s][c0 + 4];
    float bb[4] = {b.x, b.y, b.z, b.w};
    float xx[8] = {xa.x, xa.y, xa.z, xa.w, xb.x, xb.y, xb.z, xb.w};
#pragma unroll
    for (int i = 0; i < 4; ++i)
#pragma unroll
      for (int j = 0; j < 8; ++j) acc[i][j] = fmaf(bb[i], xx[j], acc[i][j]);
  }
  float* dst = Sloc + ((size_t)(k * NH + h) << 13);
#pragma unroll
  for (int i = 0; i < 4; ++i) {
    *(float4*)(dst + (d0 + i) * 128 + c0)     = make_float4(acc[i][0], acc[i][1], acc[i][2], acc[i][3]);
    *(float4*)(dst + (d0 + i) * 128 + c0 + 4) = make_float4(acc[i][4], acc[i][5], acc[i][6], acc[i][7]);
  }
}

// ---------------- sequential scan over 16 chunks (inclusive states) ----------
__global__ __launch_bounds__(256) void chunk_scan(float* __restrict__ Sloc,
    const float* __restrict__ Phi) {
  int b = blockIdx.x;
  int h = b >> 5;
  int e = (b & 31) * 256 + threadIdx.x;
  float run = Sloc[((size_t)h << 13) + e];
#pragma unroll
  for (int k = 1; k < 16; ++k) {
    float lam = expf(Phi[(k * 64 + 63) * NH + h] - Phi[(k * 64 - 1) * NH + h]);
    size_t o = ((size_t)(k * NH + h) << 13) + e;
    run = fmaf(lam, run, Sloc[o]);
    Sloc[o] = run;
  }
}

// ---------------- per-chunk output: diag quadratic + carried state + Dp*x ----
__global__ __launch_bounds__(256) void ssm_out(const float* __restrict__ proj,
    const float* __restrict__ xact, const float* __restrict__ Phi,
    const float* __restrict__ dts, const float* __restrict__ Dp,
    const float* __restrict__ Sloc, float* __restrict__ y) {
  const int k = blockIdx.x, h = blockIdx.y, zh = blockIdx.z, tid = threadIdx.x;
  __shared__ float Cst[64][68];   // [d][t]
  __shared__ float Bst[64][68];   // [d][s]; later masked S[t][s]
  __shared__ float Xs[64][68];    // [s][c]; later Sprev[d][c]
  __shared__ float phiT[64], eS[64], dS[64], eT[64];
  const int t0 = k * 64;
  const int ty = tid >> 4, tx = tid & 15, ri = ty * 4, cj = tx * 4;

#pragma unroll
  for (int u = 0; u < 4; ++u) {
    int idx = tid + u * 256, i = idx >> 4, fq = (idx & 15) * 4;
    float4 cv = *(const float4*)(proj + (size_t)(t0 + i) * NPROJ + OFF_C + h * 64 + fq);
    Cst[fq + 0][i] = cv.x; Cst[fq + 1][i] = cv.y; Cst[fq + 2][i] = cv.z; Cst[fq + 3][i] = cv.w;
    float4 bv = *(const float4*)(proj + (size_t)(t0 + i) * NPROJ + OFF_B + h * 64 + fq);
    Bst[fq + 0][i] = bv.x; Bst[fq + 1][i] = bv.y; Bst[fq + 2][i] = bv.z; Bst[fq + 3][i] = bv.w;
    float4 xv = *(const float4*)(xact + (size_t)(t0 + i) * DINNER + h * HDIM + zh * 64 + fq);
    *(float4*)&Xs[i][fq] = xv;
  }
  if (tid < 64) {
    float p = Phi[(t0 + tid) * NH + h];
    phiT[tid] = p;
    eS[tid] = fminf(-p, 80.f);
    dS[tid] = dts[(t0 + tid) * NH + h];
    eT[tid] = (k > 0) ? expf(p - Phi[(t0 - 1) * NH + h]) : 0.f;
  }
  __syncthreads();

  // S-diag = C_t . B_s
  float sreg[4][4] = {};
#pragma unroll 16
  for (int d = 0; d < 64; ++d) {
    float4 cv = *(const float4*)&Cst[d][ri];
    float4 bv = *(const float4*)&Bst[d][cj];
    float a[4] = {cv.x, cv.y, cv.z, cv.w};
    float b[4] = {bv.x, bv.y, bv.z, bv.w};
#pragma unroll
    for (int i = 0; i < 4; ++i)
#pragma unroll
      for (int j = 0; j < 4; ++j) sreg[i][j] = fmaf(a[i], b[j], sreg[i][j]);
  }
  __syncthreads();
#pragma unroll
  for (int i = 0; i < 4; ++i) {
    int ti = ri + i;
#pragma unroll
    for (int j = 0; j < 4; ++j) {
      int sj = cj + j;
      float f = (sj <= ti) ? expf(phiT[ti] + eS[sj]) * dS[sj] : 0.f;
      Bst[ti][sj] = sreg[i][j] * f;
    }
  }
  __syncthreads();

  // PV-diag
  float acc[4][4] = {};
#pragma unroll 8
  for (int j = 0; j < 64; j += 4) {
    float4 x0 = *(const float4*)&Xs[j + 0][cj];
    float4 x1 = *(const float4*)&Xs[j + 1][cj];
    float4 x2 = *(const float4*)&Xs[j + 2][cj];
    float4 x3 = *(const float4*)&Xs[j + 3][cj];
    float X0[4] = {x0.x, x0.y, x0.z, x0.w};
    float X1[4] = {x1.x, x1.y, x1.z, x1.w};
    float X2[4] = {x2.x, x2.y, x2.z, x2.w};
    float X3[4] = {x3.x, x3.y, x3.z, x3.w};
#pragma unroll
    for (int i = 0; i < 4; ++i) {
      float4 sv = *(const float4*)&Bst[ri + i][j];
#pragma unroll
      for (int c = 0; c < 4; ++c) {
        acc[i][c] = fmaf(sv.x, X0[c], acc[i][c]);
        acc[i][c] = fmaf(sv.y, X1[c], acc[i][c]);
        acc[i][c] = fmaf(sv.z, X2[c], acc[i][c]);
        acc[i][c] = fmaf(sv.w, X3[c], acc[i][c]);
      }
    }
  }
  // + Dp * x (Xs still holds this chunk's X)
  float dp = Dp[h];
#pragma unroll
  for (int i = 0; i < 4; ++i)
#pragma unroll
    for (int j = 0; j < 4; ++j) acc[i][j] = fmaf(dp, Xs[ri + i][cj + j], acc[i][j]);

  if (k > 0) {
    __syncthreads();
#pragma unroll
    for (int u = 0; u < 4; ++u) {
      int idx = tid + u * 256, d = idx >> 4, q = (idx & 15) * 4;
      *(float4*)&Xs[d][q] =
          *(const float4*)(Sloc + ((size_t)((k - 1) * NH + h) << 13) + d * 128 + zh * 64 + q);
    }
    __syncthreads();
    float a2[4][4] = {};
#pragma unroll 16
    for (int d = 0; d < 64; ++d) {
      float4 cv = *(const float4*)&Cst[d][ri];
      float4 sv = *(const float4*)&Xs[d][cj];
      float a[4] = {cv.x, cv.y, cv.z, cv.w};
      float b[4] = {sv.x, sv.y, sv.z, sv.w};
#pragma unroll
      for (int i = 0; i < 4; ++i)
#pragma unroll
        for (int j = 0; j < 4; ++j) a2[i][j] = fmaf(a[i], b[j], a2[i][j]);
    }
#pragma unroll
    for (int i = 0; i < 4; ++i)
#pragma unroll
      for (int j = 0; j < 4; ++j) acc[i][j] = fmaf(eT[ri + i], a2[i][j], acc[i][j]);
  }
#pragma unroll
  for (int i = 0; i < 4; ++i)
    *(float4*)(y + (size_t)(t0 + ri + i) * DINNER + h * HDIM + zh * 64 + cj) =
        make_float4(acc[i][0], acc[i][1], acc[i][2], acc[i][3]);
}

// ---------------- RMSNorm + gate -> split bf16 planes ----------------
__global__ __launch_bounds__(256) void norm_gate(const float* __restrict__ y,
    const float* __restrict__ proj, const float* __restrict__ nw,
    u16* __restrict__ yh, u16* __restrict__ yl) {
  int t = blockIdx.x, tid = threadIdx.x;
  float v[6], ss = 0.f;
#pragma unroll
  for (int k = 0; k < 6; ++k) {
    v[k] = y[(size_t)t * DINNER + tid + k * 256];
    ss = fmaf(v[k], v[k], ss);
  }
#pragma unroll
  for (int d = 1; d < 64; d <<= 1) ss += __shfl_xor(ss, d);
  __shared__ float wsum[4];
  int wv = tid >> 6;
  if ((tid & 63) == 0) wsum[wv] = ss;
  __syncthreads();
  float tot = wsum[0] + wsum[1] + wsum[2] + wsum[3];
  float rms = rsqrtf(tot / 1536.f + 1e-5f);
#pragma unroll
  for (int k = 0; k < 6; ++k) {
    int c = tid + k * 256;
    float z = proj[(size_t)t * NPROJ + OFF_Z + c];
    float sz = z / (1.f + expf(-z));
    float val = v[k] * rms * nw[c] * sz;
    u16 hh = f2b(val);
    yh[(size_t)t * DINNER + c] = hh;
    yl[(size_t)t * DINNER + c] = f2b(val - b2f(hh));
  }
}

extern "C" void kernel_launch(void* const* d_in, const int* in_sizes, int n_in,
                              void* d_out, int out_size, void* d_ws, size_t ws_size,
                              hipStream_t stream) {
  const float* x       = (const float*)d_in[0];
  const float* W_in    = (const float*)d_in[1];
  const float* conv_w  = (const float*)d_in[2];
  const float* conv_b  = (const float*)d_in[3];
  const float* A_log   = (const float*)d_in[4];
  const float* Dp      = (const float*)d_in[5];
  const float* dt_bias = (const float*)d_in[6];
  const float* W_out   = (const float*)d_in[7];
  const float* norm_w  = (const float*)d_in[8];
  float* out = (float*)d_out;

  char* base = (char*)d_ws;
  size_t o = 0;
  auto alloc = [&](size_t bytes) { char* r = base + o; o += (bytes + 255) & ~(size_t)255; return r; };
  float* proj = (float*)alloc((size_t)LSEQ * NPROJ * 4);
  float* xact = (float*)alloc((size_t)LSEQ * DINNER * 4);
  float* ybuf = (float*)alloc((size_t)LSEQ * DINNER * 4);
  float* Phi  = (float*)alloc((size_t)LSEQ * NH * 4);
  float* dtsb = (float*)alloc((size_t)LSEQ * NH * 4);
  float* Sloc = (float*)alloc((size_t)16 * NH * 64 * 128 * 4);
  u16* Ahi  = (u16*)alloc((size_t)LSEQ * 768 * 2);
  u16* Alo  = (u16*)alloc((size_t)LSEQ * 768 * 2);
  u16* Whi  = (u16*)alloc((size_t)NPAD * 768 * 2);
  u16* Wlo  = (u16*)alloc((size_t)NPAD * 768 * 2);
  u16* Wohi = (u16*)alloc((size_t)768 * DINNER * 2);
  u16* Wolo = (u16*)alloc((size_t)768 * DINNER * 2);
  u16* Yh   = (u16*)alloc((size_t)LSEQ * DINNER * 2);
  u16* Yl   = (u16*)alloc((size_t)LSEQ * DINNER * 2);
  float* Pp = proj;   // out-proj partials alias proj (dead by then): 2*1024*768*4 = 6.3MB

  // split all f32 operands into bf16 hi/lo planes (one launch)
  ksplit_all<<<dim3((S0N + S1N + S2N) / 256), 256, 0, stream>>>(
      x, W_in, W_out, Ahi, Alo, Whi, Wlo, Wohi, Wolo);
  // in-projection: 64x128 tiles, XCD-striped, 640 blocks
  gemm3<64, 128, 0, true><<<dim3(640), 256, 0, stream>>>(
      Ahi, Alo, Whi, Wlo, proj, 768, 768, 768, NPROJ, NPROJ);
  // conv + silu
  conv_silu<<<dim3(LSEQ * DINNER / 256), 256, 0, stream>>>(proj, conv_w, conv_b, xact);
  // dt & Phi
  dtphi<<<dim3(NH), 256, 0, stream>>>(proj, A_log, dt_bias, Phi, dtsb);
  // chunked SSM
  chunk_state<<<dim3(16, NH), 256, 0, stream>>>(proj, xact, Phi, dtsb, Sloc);
  chunk_scan<<<dim3(NH * 32), 256, 0, stream>>>(Sloc, Phi);
  ssm_out<<<dim3(16, NH, 2), 256, 0, stream>>>(proj, xact, Phi, dtsb, Dp, Sloc, ybuf);
  // norm + gate -> bf16 planes
  norm_gate<<<dim3(LSEQ), 256, 0, stream>>>(ybuf, proj, norm_w, Yh, Yl);
  // out-projection: split-K=2, 64x64 tiles, 384 blocks -> partials in Pp
  gemm3<64, 64, 1, false><<<dim3(384), 256, 0, stream>>>(
      Yh, Yl, Wohi, Wolo, Pp, 1536, 1536, 768, 768, 768);
  // reduce partials
  addk<<<dim3(LSEQ * 768 / 4 / 256), 256, 0, stream>>>(Pp, out);
}